// Round 5
// baseline (310.606 us; speedup 1.0000x reference)
//
#include <hip/hip_runtime.h>
#include <hip/hip_bf16.h>

#define HID 64
#define INDIM 128
#define BK_SHIFT 7            // 128 nodes per bucket
#define BK_NODES 128
#define NBK_MAX 1024          // supports N <= 131072
#define PB_BLOCKS 1024
#define PB_MAXI 8             // supports E <= 1024*256*8 = 2.097M

typedef __attribute__((ext_vector_type(8))) short bf16x8;
typedef __attribute__((ext_vector_type(4))) float f32x4;

// 16B load from a 4B-aligned address (sorted_src + arbitrary e)
struct __attribute__((packed, aligned(4))) u4u { unsigned x, y, z, w; };

static __device__ __forceinline__ short f2bf(float f) {
    __hip_bfloat16 h = __float2bfloat16(f);
    return *reinterpret_cast<short*>(&h);
}
static __device__ __forceinline__ float bf2f(short s) {
    return __uint_as_float(((unsigned)(unsigned short)s) << 16);
}

// ---------- CSR build ----------
// cursor[] and deg[] zero-initialized by one hipMemsetAsync (contiguous in ws).
// bpart also accumulates per-node in-degree via fire-and-forget global atomics,
// which breaks the bsort->gemm1 dinv dependency and lets them run fused/overlapped.

__global__ __launch_bounds__(256) void bpart_k(const int* __restrict__ src,
                                               const int* __restrict__ dst,
                                               int* __restrict__ cursor,
                                               int* __restrict__ deg,
                                               int* __restrict__ bucketed, int E, int cap) {
    __shared__ int hist[NBK_MAX];
    __shared__ int base[NBK_MAX];
    for (int i = threadIdx.x; i < NBK_MAX; i += 256) hist[i] = 0;
    __syncthreads();
    int code[PB_MAXI];
#pragma unroll
    for (int i = 0; i < PB_MAXI; i++) {
        code[i] = -1;
        long e = (long)i * (PB_BLOCKS * 256) + (long)blockIdx.x * 256 + threadIdx.x;
        if (e < E) {
            int d = dst[e];
            int b = d >> BK_SHIFT;
            atomicAdd(&deg[d], 1);            // in-degree (no return use -> no wait)
            int p = atomicAdd(&hist[b], 1);   // p < 4096 (block edge total)
            code[i] = (b << 12) | p;
        }
    }
    __syncthreads();
    for (int i = threadIdx.x; i < NBK_MAX; i += 256)
        base[i] = hist[i] ? (i * cap + atomicAdd(&cursor[i], hist[i])) : 0;
    __syncthreads();
#pragma unroll
    for (int i = 0; i < PB_MAXI; i++) {
        long e = (long)i * (PB_BLOCKS * 256) + (long)blockIdx.x * 256 + threadIdx.x;
        if (e < E) {
            int b = code[i] >> 12, p = code[i] & 0xFFF;
            int pos = base[b] + p;
            if (pos < (b + 1) * cap)          // overflow guard (never hit for random dst)
                bucketed[pos] = src[e] | ((dst[e] & (BK_NODES - 1)) << 20);
        }
    }
}

// ---------- fused bsort + gemm1 + wfrag-build bodies ----------

// one block per 128-node bucket: counting sort; emits rowbeg/rowend (dinv moved to gemm1)
static __device__ __forceinline__ void bsort_body(char* pool, int b,
                                                  const int* __restrict__ bucketed,
                                                  const int* __restrict__ cursor,
                                                  int* __restrict__ rowbeg,
                                                  int* __restrict__ rowend,
                                                  int* __restrict__ sorted_src,
                                                  int N, int cap) {
    int* ldeg = (int*)pool;                   // [128]
    int* lscn = ldeg + BK_NODES;              // [128]
    int* lcur = lscn + BK_NODES;              // [128]
    int t = threadIdx.x;
    int nstart = b << BK_SHIFT;
    int ncnt = min(BK_NODES, N - nstart);
    int estart = b * cap;
    int ecnt = cursor[b];                     // count (cursor started at 0)
    if (t < BK_NODES) ldeg[t] = 0;
    __syncthreads();
    for (int j = t; j < ecnt; j += 256)
        atomicAdd(&ldeg[bucketed[estart + j] >> 20], 1);
    __syncthreads();
    int myv = (t < BK_NODES) ? ldeg[t] : 0;
    if (t < BK_NODES) lscn[t] = myv;
    __syncthreads();
    for (int off = 1; off < BK_NODES; off <<= 1) {
        int x = (t < BK_NODES && t >= off) ? lscn[t - off] : 0;
        __syncthreads();
        if (t < BK_NODES) lscn[t] += x;
        __syncthreads();
    }
    if (t < ncnt) {
        int excl = lscn[t] - myv;
        rowbeg[nstart + t] = estart + excl;
        rowend[nstart + t] = estart + lscn[t];
        lcur[t] = excl;
    }
    __syncthreads();
    for (int j = t; j < ecnt; j += 256) {
        int eg = bucketed[estart + j];
        int p = atomicAdd(&lcur[eg >> 20], 1);
        sorted_src[estart + p] = eg & 0xFFFFF;
    }
}

// hs1[M,64] = ((x[M,128] @ W1) * dinv) in bf16, MFMA with hi/lo bf16 split.
// dinv computed here from deg (bpart's atomics) and published for fgather.
static __device__ __forceinline__ void gemm1_body(char* pool, int blk,
                                                  const float* __restrict__ A,
                                                  const float* __restrict__ W,
                                                  const int* __restrict__ deg,
                                                  float* __restrict__ dinv,
                                                  __hip_bfloat16* __restrict__ C, int M) {
    short* WH = (short*)pool;                 // 16KB: [(kt*4+nt)*64 + lane][8]
    short* WL = (short*)(pool + 16384);       // 16KB
    int t = threadIdx.x;
    int lane = t & 63;
    int wid = t >> 6;
    int q = lane & 15, g = lane >> 4;
    int tile = blk << 6;

#pragma unroll
    for (int s = 0; s < 4; s++) {
        int sid = t + s * 256;
        int col = (((sid >> 6) & 3) << 4) + (sid & 15);
        int kb  = ((sid >> 8) << 5) + (((sid >> 4) & 3) << 3);
        union { short s[8]; uint4 u; } ph, pl;
#pragma unroll
        for (int i = 0; i < 8; i++) {
            float w = W[(kb + i) * HID + col];
            short h = f2bf(w);
            ph.s[i] = h;
            pl.s[i] = f2bf(w - bf2f(h));
        }
        *((uint4*)WH + sid) = ph.u;
        *((uint4*)WL + sid) = pl.u;
    }
    __syncthreads();

    int arow = tile + (wid << 4) + q;
    if (arow >= M) arow = M - 1;              // clamped rows discarded at store
    const float* ap = A + (long)arow * INDIM + (g << 3);
    f32x4 acc[4] = {};
#pragma unroll
    for (int kt = 0; kt < 4; kt++) {
        float4 x0 = *(const float4*)(ap + (kt << 5));
        float4 x1 = *(const float4*)(ap + (kt << 5) + 4);
        float xv[8] = {x0.x, x0.y, x0.z, x0.w, x1.x, x1.y, x1.z, x1.w};
        union { short s[8]; bf16x8 v; } ah, al;
#pragma unroll
        for (int i = 0; i < 8; i++) {
            short h = f2bf(xv[i]);
            ah.s[i] = h;
            al.s[i] = f2bf(xv[i] - bf2f(h));
        }
#pragma unroll
        for (int nt = 0; nt < 4; nt++) {
            int soff = ((((kt << 2) + nt) << 6) + lane) << 4;
            bf16x8 bh = *(const bf16x8*)((const char*)WH + soff);
            bf16x8 bl = *(const bf16x8*)((const char*)WL + soff);
            acc[nt] = __builtin_amdgcn_mfma_f32_16x16x32_bf16(ah.v, bh, acc[nt], 0, 0, 0);
            acc[nt] = __builtin_amdgcn_mfma_f32_16x16x32_bf16(ah.v, bl, acc[nt], 0, 0, 0);
            acc[nt] = __builtin_amdgcn_mfma_f32_16x16x32_bf16(al.v, bh, acc[nt], 0, 0, 0);
        }
    }
    // C/D layout: col = (nt<<4)+q, row = (g<<2)+reg. dinv from deg; scale; store bf16.
    int rbase = tile + (wid << 4) + (g << 2);
#pragma unroll
    for (int reg = 0; reg < 4; reg++) {
        int node = rbase + reg;
        if (node < M) {
            float di = rsqrtf(1.0f + (float)deg[node]);
            if (q == 0) dinv[node] = di;
            __hip_bfloat16* out = C + ((long)node << 6) + q;
#pragma unroll
            for (int nt = 0; nt < 4; nt++)
                out[nt << 4] = __float2bfloat16(acc[nt][reg] * di);
        }
    }
}

// build the hi/lo bf16 B-fragment planes for a 64x64 weight into global workspace:
// slot sid holds B[kb..kb+7][col]; plane H at [0,512), plane L at [512,1024) slots.
static __device__ __forceinline__ void wfrag_body(const float* __restrict__ Wsrc,
                                                  short* __restrict__ out) {
    int t = threadIdx.x;
#pragma unroll
    for (int s = 0; s < 2; s++) {
        int sid = t + s * 256;
        int col = (((sid >> 6) & 3) << 4) + (sid & 15);
        int kb  = ((sid >> 8) << 5) + (((sid >> 4) & 3) << 3);
        union { short s[8]; uint4 u; } ph, pl;
#pragma unroll
        for (int i = 0; i < 8; i++) {
            float w = Wsrc[(kb + i) * 64 + col];
            short h = f2bf(w);
            ph.s[i] = h;
            pl.s[i] = f2bf(w - bf2f(h));
        }
        ((uint4*)out)[sid] = ph.u;
        ((uint4*)out)[512 + sid] = pl.u;
    }
}

// fused dispatch: [0,nb) bsort | [nb,nb+g1b) gemm1 | [nb+g1b,nb+g1b+2) wfrag builders.
// bsort and gemm1 are independent (deg from bpart) -> they overlap on the machine.
__global__ __launch_bounds__(256) void fused_k(const int* __restrict__ bucketed,
                                               const int* __restrict__ cursor,
                                               int* __restrict__ rowbeg,
                                               int* __restrict__ rowend,
                                               int* __restrict__ sorted_src,
                                               int N, int cap, int nb, int g1b,
                                               const float* __restrict__ A,
                                               const float* __restrict__ W1,
                                               const int* __restrict__ deg,
                                               float* __restrict__ dinv,
                                               __hip_bfloat16* __restrict__ hs1,
                                               const float* __restrict__ W2,
                                               const float* __restrict__ Wfc,
                                               short* __restrict__ wf2,
                                               short* __restrict__ wffc) {
    __shared__ __align__(16) char pool[32768];
    int bx = blockIdx.x;
    if (bx < nb)
        bsort_body(pool, bx, bucketed, cursor, rowbeg, rowend, sorted_src, N, cap);
    else if (bx < nb + g1b)
        gemm1_body(pool, bx - nb, A, W1, deg, dinv, hs1, N);
    else if (bx == nb + g1b)
        wfrag_body(W2, wf2);
    else
        wfrag_body(Wfc, wffc);
}

// ---------- fused gather + next-layer GEMM ----------

#define LO16(u) __uint_as_float((u) << 16)
#define HI16(u) __uint_as_float((u) & 0xffff0000u)
#define ACC8(v)                                            \
    do {                                                   \
        a[0] += LO16((v).x); a[1] += HI16((v).x);          \
        a[2] += LO16((v).y); a[3] += HI16((v).y);          \
        a[4] += LO16((v).z); a[5] += HI16((v).z);          \
        a[6] += LO16((v).w); a[7] += HI16((v).w);          \
    } while (0)

// Block = 4 waves = 64-node tile. W-fragments are pre-built in global (wf): phase C
// reads them directly (L1-resident, 16KB) -> LDS is only RH/RL (16KB) -> 8 blocks/CU
// (wave-cap) vs 5 before; no W-staging prologue. Phase B: 2 nodes per wave-round,
// 32 edges per shot (2 idx dwordx4 + 8 data dwordx4 in flight). Over-reads clamp by
// VALUE to the zeroed guard row hs[n].
template <bool HS_OUT>
__global__ __launch_bounds__(256) void fgather_k(void* __restrict__ outp,
                                                 const __hip_bfloat16* __restrict__ hs,
                                                 const float* __restrict__ dinv,
                                                 const float* __restrict__ biasA,
                                                 const short* __restrict__ wf,
                                                 const float* __restrict__ biasB,
                                                 const int* __restrict__ rowbeg,
                                                 const int* __restrict__ rowend,
                                                 const int* __restrict__ sorted_src, int n) {
    __shared__ __align__(16) short RH[64 * 64];   // A-tile hi: [row][8 x 16B-block ^ row&7]
    __shared__ __align__(16) short RL[64 * 64];   // A-tile lo

    int t = threadIdx.x;
    int lane = t & 63;
    int wid = __builtin_amdgcn_readfirstlane(t >> 6);
    int q = lane & 15, g = lane >> 4;             // phase C coords
    int tile = blockIdx.x << 6;

    // ---- Phase B: aggregation, 2 nodes per wave-round ----
    int half = lane >> 5;                     // which node of the pair
    int g2 = (lane >> 3) & 3;                 // edge sub-stream 0..3
    int f8 = lane & 7;                        // feature octet 0..7
    int fo8 = f8 << 3;
    int rbv = 0, rev = 0;
    {
        int ndl = tile + (wid << 4) + (lane & 15);
        if (lane < 16 && ndl < n) { rbv = rowbeg[ndl]; rev = rowend[ndl]; }
    }
    __align__(16) float bb8[8];
    *(float4*)(bb8)     = *(const float4*)(biasA + fo8);
    *(float4*)(bb8 + 4) = *(const float4*)(biasA + fo8 + 4);

    for (int r = 0; r < 8; r++) {
        int row = (wid << 4) + (r << 1) + half;
        int nd = tile + row;
        int e0 = __shfl(rbv, row & 15);
        int e1 = __shfl(rev, row & 15);
        float a[8] = {0.f, 0.f, 0.f, 0.f, 0.f, 0.f, 0.f, 0.f};
        int e = e0;
        for (; e + 32 <= e1; e += 32) {       // 32 edges per node per iter
            u4u iv0 = *(const u4u*)(sorted_src + e + (g2 << 2));
            u4u iv1 = *(const u4u*)(sorted_src + e + 16 + (g2 << 2));
            uint4 v0 = *(const uint4*)(hs + (((int)iv0.x << 6) + fo8));
            uint4 v1 = *(const uint4*)(hs + (((int)iv0.y << 6) + fo8));
            uint4 v2 = *(const uint4*)(hs + (((int)iv0.z << 6) + fo8));
            uint4 v3 = *(const uint4*)(hs + (((int)iv0.w << 6) + fo8));
            uint4 v4 = *(const uint4*)(hs + (((int)iv1.x << 6) + fo8));
            uint4 v5 = *(const uint4*)(hs + (((int)iv1.y << 6) + fo8));
            uint4 v6 = *(const uint4*)(hs + (((int)iv1.z << 6) + fo8));
            uint4 v7 = *(const uint4*)(hs + (((int)iv1.w << 6) + fo8));
            ACC8(v0); ACC8(v1); ACC8(v2); ACC8(v3);
            ACC8(v4); ACC8(v5); ACC8(v6); ACC8(v7);
        }
        if (e < e1) {                         // one clamped 32-edge block
            int last = e1 - 1;
            int b0 = e + (g2 << 2);
            int b1 = b0 + 16;
            u4u iv0 = *(const u4u*)(sorted_src + b0);
            u4u iv1 = *(const u4u*)(sorted_src + b1);
            int i0 = (b0     <= last) ? (int)iv0.x : n;
            int i1 = (b0 + 1 <= last) ? (int)iv0.y : n;
            int i2 = (b0 + 2 <= last) ? (int)iv0.z : n;
            int i3 = (b0 + 3 <= last) ? (int)iv0.w : n;
            int i4 = (b1     <= last) ? (int)iv1.x : n;
            int i5 = (b1 + 1 <= last) ? (int)iv1.y : n;
            int i6 = (b1 + 2 <= last) ? (int)iv1.z : n;
            int i7 = (b1 + 3 <= last) ? (int)iv1.w : n;
            uint4 v0 = *(const uint4*)(hs + ((i0 << 6) + fo8));
            uint4 v1 = *(const uint4*)(hs + ((i1 << 6) + fo8));
            uint4 v2 = *(const uint4*)(hs + ((i2 << 6) + fo8));
            uint4 v3 = *(const uint4*)(hs + ((i3 << 6) + fo8));
            uint4 v4 = *(const uint4*)(hs + ((i4 << 6) + fo8));
            uint4 v5 = *(const uint4*)(hs + ((i5 << 6) + fo8));
            uint4 v6 = *(const uint4*)(hs + ((i6 << 6) + fo8));
            uint4 v7 = *(const uint4*)(hs + ((i7 << 6) + fo8));
            ACC8(v0); ACC8(v1); ACC8(v2); ACC8(v3);
            ACC8(v4); ACC8(v5); ACC8(v6); ACC8(v7);
        }
        // merge the 4 edge sub-streams (within each 32-lane half)
#pragma unroll
        for (int k = 0; k < 8; k++) a[k] += __shfl_xor(a[k], 8);
#pragma unroll
        for (int k = 0; k < 8; k++) a[k] += __shfl_xor(a[k], 16);
        // self-loop term (zero row for OOB)
        int snd = nd < n ? nd : n;
        uint4 sv = *(const uint4*)(hs + ((snd << 6) + fo8));
        ACC8(sv);
        float di = dinv[nd < n ? nd : 0];
        union { short s[8]; uint4 u; } ph, pl;
#pragma unroll
        for (int k = 0; k < 8; k++) {
            float rk = fmaxf(fmaf(di, a[k], bb8[k]), 0.f);
            short h = f2bf(rk);
            ph.s[k] = h;
            pl.s[k] = f2bf(rk - bf2f(h));
        }
        if (g2 == 0 && nd < n) {              // 8 lanes per half write the row
            int boff = row * 128 + ((f8 ^ (row & 7)) << 4);
            *(uint4*)((char*)RH + boff) = ph.u;
            *(uint4*)((char*)RL + boff) = pl.u;
        }
    }
    __syncthreads();                          // RH/RL staging -> Phase C
    // (RH/RL rows are wave-private; barrier-removal via lgkmcnt+sched_barrier is a
    //  candidate for next round once this structure's counters are read.)

    // ---- Phase C: FC via MFMA, B-frags straight from global (L1) ----
    const bf16x8* wfv = (const bf16x8*)wf;
    f32x4 acc[4] = {};
#pragma unroll
    for (int kt = 0; kt < 2; kt++) {
        int arow = (wid << 4) + q;            // arow&7 == q&7 == write-side row&7
        int aoff = arow * 128 + ((((kt << 2) + g) ^ (q & 7)) << 4);
        bf16x8 ah = *(const bf16x8*)((const char*)RH + aoff);
        bf16x8 al = *(const bf16x8*)((const char*)RL + aoff);
#pragma unroll
        for (int nt = 0; nt < 4; nt++) {
            int sid = (((kt << 2) + nt) << 6) + lane;
            bf16x8 bh = wfv[sid];
            bf16x8 bl = wfv[512 + sid];
            acc[nt] = __builtin_amdgcn_mfma_f32_16x16x32_bf16(ah, bh, acc[nt], 0, 0, 0);
            acc[nt] = __builtin_amdgcn_mfma_f32_16x16x32_bf16(ah, bl, acc[nt], 0, 0, 0);
            acc[nt] = __builtin_amdgcn_mfma_f32_16x16x32_bf16(al, bh, acc[nt], 0, 0, 0);
        }
    }

    // ---- epilogue: C[row = (g<<2)+reg][col = (nt<<4)+q] ----
    int rbase = tile + (wid << 4);
    if (HS_OUT) {
        __hip_bfloat16* out = (__hip_bfloat16*)outp;
#pragma unroll
        for (int reg = 0; reg < 4; reg++) {
            int node = rbase + (g << 2) + reg;
            if (node < n) {
                float di = dinv[node];
#pragma unroll
                for (int nt = 0; nt < 4; nt++)
                    out[(node << 6) + (nt << 4) + q] = __float2bfloat16(acc[nt][reg] * di);
            }
        }
    } else {
        float* out = (float*)outp;
        float bB[4];
#pragma unroll
        for (int nt = 0; nt < 4; nt++) bB[nt] = biasB[(nt << 4) + q];
#pragma unroll
        for (int reg = 0; reg < 4; reg++) {
            int node = rbase + (g << 2) + reg;
            if (node < n) {
#pragma unroll
                for (int nt = 0; nt < 4; nt++)
                    out[(node << 6) + (nt << 4) + q] = acc[nt][reg] + bB[nt];
            }
        }
    }
}

extern "C" void kernel_launch(void* const* d_in, const int* in_sizes, int n_in,
                              void* d_out, int out_size, void* d_ws, size_t ws_size,
                              hipStream_t stream) {
    const float* x   = (const float*)d_in[0];
    const int*   ei  = (const int*)d_in[1];
    const float* W1  = (const float*)d_in[2];
    const float* b1  = (const float*)d_in[3];
    const float* W2  = (const float*)d_in[4];
    const float* b2  = (const float*)d_in[5];
    const float* Wfc = (const float*)d_in[6];
    const float* bfc = (const float*)d_in[7];

    int N = in_sizes[0] / INDIM;
    int E = in_sizes[1] / 2;
    const int* src = ei;       // edge_index row 0
    const int* dst = ei + E;   // edge_index row 1
    int nb = (N + BK_NODES - 1) >> BK_SHIFT;          // 782 buckets
    int cap = (2 * E / nb + 63) & ~63;                // 2x mean bucket load
    if (cap < 4096) cap = 4096;
    int g1b = (N + 63) / 64;

    char* ws = (char*)d_ws;
    auto alloc = [&](size_t bytes) {
        char* p = ws;
        ws += (bytes + 15) & ~(size_t)15;
        return p;
    };
    int*   rowbeg     = (int*)alloc(sizeof(int) * (size_t)N);
    int*   rowend     = (int*)alloc(sizeof(int) * (size_t)N);
    float* dinv       = (float*)alloc(sizeof(float) * (size_t)N);
    int*   cursor     = (int*)alloc(sizeof(int) * NBK_MAX);   // 4KB, 16-aligned
    int*   deg        = (int*)alloc(sizeof(int) * (size_t)N); // contiguous after cursor
    int*   sorted_src = (int*)alloc(sizeof(int) * (size_t)nb * cap);
    short* wf2        = (short*)alloc(sizeof(short) * 1024 * 8);  // 16KB frag planes
    short* wffc       = (short*)alloc(sizeof(short) * 1024 * 8);
    // big region: bucketed (int, nb*cap) during build; hs2 (bf16, (N+1)*64) after
    // (lifetimes disjoint: bucketed dead after fused_k; hs2 written by fgather<true>).
    size_t big_bytes = sizeof(int) * (size_t)nb * cap;
    size_t hs_bytes  = sizeof(__hip_bfloat16) * (size_t)(N + 1) * HID;
    char*  big       = alloc(big_bytes > hs_bytes ? big_bytes : hs_bytes);
    int*   bucketed  = (int*)big;
    __hip_bfloat16* hs2 = (__hip_bfloat16*)big;
    // hs1 lives in d_out (25.6MB f32 region; hs1 needs 12.8MB bf16 + 128B guard).
    // It is dead before fgather<false> overwrites d_out with the final f32 output.
    __hip_bfloat16* hs1 = (__hip_bfloat16*)d_out;
    float* outp      = (float*)d_out;

    // cursor+deg are contiguous (cursor is 4KB, 16B-aligned) -> single memset.
    hipMemsetAsync(cursor, 0, sizeof(int) * (NBK_MAX + (size_t)N), stream);
    // hs1 guard row (in d_out scratch): nothing touches d_out before gemm1.
    hipMemsetAsync((char*)hs1 + (size_t)N * HID * 2, 0, HID * 2, stream);

    bpart_k<<<PB_BLOCKS, 256, 0, stream>>>(src, dst, cursor, deg, bucketed, E, cap);
    fused_k<<<nb + g1b + 2, 256, 0, stream>>>(bucketed, cursor, rowbeg, rowend,
                                              sorted_src, N, cap, nb, g1b,
                                              x, W1, deg, dinv, hs1,
                                              W2, Wfc, wf2, wffc);
    // hs2 guard row (big region is free of bucketed only after fused_k)
    hipMemsetAsync((char*)hs2 + (size_t)N * HID * 2, 0, HID * 2, stream);

    fgather_k<true><<<(N + 63) / 64, 256, 0, stream>>>(hs2, hs1, dinv, b1, wf2, nullptr,
                                                       rowbeg, rowend, sorted_src, N);
    fgather_k<false><<<(N + 63) / 64, 256, 0, stream>>>(outp, hs2, dinv, b2, wffc, bfc,
                                                        rowbeg, rowend, sorted_src, N);
}

// Round 6
// 259.397 us; speedup vs baseline: 1.1974x; 1.1974x over previous
//
#include <hip/hip_runtime.h>
#include <hip/hip_bf16.h>

#define HID 64
#define INDIM 128
#define BK_SHIFT 7            // 128 nodes per bucket
#define BK_NODES 128
#define NBK_MAX 1024          // supports N <= 131072
#define PB_BLOCKS 1024
#define PB_MAXI 8             // supports E <= 1024*256*8 = 2.097M

typedef __attribute__((ext_vector_type(8))) short bf16x8;
typedef __attribute__((ext_vector_type(4))) float f32x4;

// 16B load from a 4B-aligned address (sorted_src + arbitrary e)
struct __attribute__((packed, aligned(4))) u4u { unsigned x, y, z, w; };

static __device__ __forceinline__ short f2bf(float f) {
    __hip_bfloat16 h = __float2bfloat16(f);
    return *reinterpret_cast<short*>(&h);
}
static __device__ __forceinline__ float bf2f(short s) {
    return __uint_as_float(((unsigned)(unsigned short)s) << 16);
}

// ---------- CSR build: fixed-capacity buckets ----------
// cursor[] zero-initialized by hipMemsetAsync; bucket base offset b*cap added at claim.
// NOTE (R4 post-mortem): per-edge global atomicAdd on deg[] cost +50us in bpart
// (random 64B RMW line traffic). deg/dinv stays bucket-local in bsort's LDS.

__global__ __launch_bounds__(256) void bpart_k(const int* __restrict__ src,
                                               const int* __restrict__ dst,
                                               int* __restrict__ cursor,
                                               int* __restrict__ bucketed, int E, int cap) {
    __shared__ int hist[NBK_MAX];
    __shared__ int base[NBK_MAX];
    for (int i = threadIdx.x; i < NBK_MAX; i += 256) hist[i] = 0;
    __syncthreads();
    int code[PB_MAXI];
#pragma unroll
    for (int i = 0; i < PB_MAXI; i++) {
        code[i] = -1;
        long e = (long)i * (PB_BLOCKS * 256) + (long)blockIdx.x * 256 + threadIdx.x;
        if (e < E) {
            int b = dst[e] >> BK_SHIFT;
            int p = atomicAdd(&hist[b], 1);   // p < 2048 (block edge total)
            code[i] = (b << 12) | p;
        }
    }
    __syncthreads();
    for (int i = threadIdx.x; i < NBK_MAX; i += 256)
        base[i] = hist[i] ? (i * cap + atomicAdd(&cursor[i], hist[i])) : 0;
    __syncthreads();
#pragma unroll
    for (int i = 0; i < PB_MAXI; i++) {
        long e = (long)i * (PB_BLOCKS * 256) + (long)blockIdx.x * 256 + threadIdx.x;
        if (e < E) {
            int b = code[i] >> 12, p = code[i] & 0xFFF;
            int pos = base[b] + p;
            if (pos < (b + 1) * cap)          // overflow guard (never hit for random dst)
                bucketed[pos] = src[e] | ((dst[e] & (BK_NODES - 1)) << 20);
        }
    }
}

// build the hi/lo bf16 B-fragment planes for a 64x64 weight into global workspace:
// slot sid holds B[kb..kb+7][col]; plane H at [0,512), plane L at [512,1024) slots.
static __device__ __forceinline__ void wfrag_body(const float* __restrict__ Wsrc,
                                                  short* __restrict__ out) {
    int t = threadIdx.x;
#pragma unroll
    for (int s = 0; s < 2; s++) {
        int sid = t + s * 256;
        int col = (((sid >> 6) & 3) << 4) + (sid & 15);
        int kb  = ((sid >> 8) << 5) + (((sid >> 4) & 3) << 3);
        union { short s[8]; uint4 u; } ph, pl;
#pragma unroll
        for (int i = 0; i < 8; i++) {
            float w = Wsrc[(kb + i) * 64 + col];
            short h = f2bf(w);
            ph.s[i] = h;
            pl.s[i] = f2bf(w - bf2f(h));
        }
        ((uint4*)out)[sid] = ph.u;
        ((uint4*)out)[512 + sid] = pl.u;
    }
}

// blocks [0,nb): one block per 128-node bucket: counting sort; emits rowbeg/rowend+dinv.
// blocks nb, nb+1: build W2/Wfc MFMA fragment planes (no LDS; trivial).
__global__ __launch_bounds__(256) void bsort_k(const int* __restrict__ bucketed,
                                               const int* __restrict__ cursor,
                                               int* __restrict__ rowbeg,
                                               int* __restrict__ rowend,
                                               int* __restrict__ sorted_src,
                                               float* __restrict__ dinv, int N, int cap,
                                               int nb,
                                               const float* __restrict__ W2,
                                               const float* __restrict__ Wfc,
                                               short* __restrict__ wf2,
                                               short* __restrict__ wffc) {
    __shared__ int deg[BK_NODES];
    __shared__ int scn[BK_NODES];
    __shared__ int cur[BK_NODES];
    int b = blockIdx.x, t = threadIdx.x;
    if (b >= nb) {
        wfrag_body(b == nb ? W2 : Wfc, b == nb ? wf2 : wffc);
        return;
    }
    int nstart = b << BK_SHIFT;
    int ncnt = min(BK_NODES, N - nstart);
    int estart = b * cap;
    int ecnt = cursor[b];                     // count (cursor started at 0)
    if (t < BK_NODES) deg[t] = 0;
    __syncthreads();
    for (int j = t; j < ecnt; j += 256)
        atomicAdd(&deg[bucketed[estart + j] >> 20], 1);
    __syncthreads();
    int myv = (t < BK_NODES) ? deg[t] : 0;
    if (t < BK_NODES) scn[t] = myv;
    __syncthreads();
    for (int off = 1; off < BK_NODES; off <<= 1) {
        int x = (t < BK_NODES && t >= off) ? scn[t - off] : 0;
        __syncthreads();
        if (t < BK_NODES) scn[t] += x;
        __syncthreads();
    }
    if (t < ncnt) {
        int excl = scn[t] - myv;
        rowbeg[nstart + t] = estart + excl;
        rowend[nstart + t] = estart + scn[t];
        dinv[nstart + t] = rsqrtf(1.0f + (float)myv);  // self-loop + in-degree
        cur[t] = excl;
    }
    __syncthreads();
    for (int j = t; j < ecnt; j += 256) {
        int eg = bucketed[estart + j];
        int p = atomicAdd(&cur[eg >> 20], 1);
        sorted_src[estart + p] = eg & 0xFFFFF;
    }
}

// ---------- compute ----------

// hs1[M,64] = ((x[M,128] @ W1) * dinv) in bf16, via MFMA with hi/lo bf16 split.
// x = xh + xl, W = wh + wl; acc = xh*wh + xh*wl + xl*wh (dropped xl*wl ~2^-26 rel).
// A-frag layout: row = lane&15, k = (lane>>4)*8+i -> A-frags load DIRECTLY from x.
// Block = 4 waves = 64 rows; 4 k-tiles x 4 nt x 3 = 48 MFMA.
__global__ __launch_bounds__(256) void gemm1_k(const float* __restrict__ A,
                                               const float* __restrict__ W,
                                               const float* __restrict__ dinv,
                                               __hip_bfloat16* __restrict__ C, int M) {
    __shared__ __align__(16) short WH[1024 * 8];   // 16KB: [(kt*4+nt)*64 + lane][8]
    __shared__ __align__(16) short WL[1024 * 8];   // 16KB
    int t = threadIdx.x;
    int lane = t & 63;
    int wid = t >> 6;
    int q = lane & 15, g = lane >> 4;
    int tile = blockIdx.x << 6;

#pragma unroll
    for (int s = 0; s < 4; s++) {
        int sid = t + s * 256;
        int col = (((sid >> 6) & 3) << 4) + (sid & 15);
        int kb  = ((sid >> 8) << 5) + (((sid >> 4) & 3) << 3);
        union { short s[8]; uint4 u; } ph, pl;
#pragma unroll
        for (int i = 0; i < 8; i++) {
            float w = W[(kb + i) * HID + col];
            short h = f2bf(w);
            ph.s[i] = h;
            pl.s[i] = f2bf(w - bf2f(h));
        }
        *((uint4*)WH + sid) = ph.u;
        *((uint4*)WL + sid) = pl.u;
    }
    __syncthreads();

    int arow = tile + (wid << 4) + q;
    if (arow >= M) arow = M - 1;              // clamped rows discarded at store
    const float* ap = A + (long)arow * INDIM + (g << 3);
    f32x4 acc[4] = {};
#pragma unroll
    for (int kt = 0; kt < 4; kt++) {
        float4 x0 = *(const float4*)(ap + (kt << 5));
        float4 x1 = *(const float4*)(ap + (kt << 5) + 4);
        float xv[8] = {x0.x, x0.y, x0.z, x0.w, x1.x, x1.y, x1.z, x1.w};
        union { short s[8]; bf16x8 v; } ah, al;
#pragma unroll
        for (int i = 0; i < 8; i++) {
            short h = f2bf(xv[i]);
            ah.s[i] = h;
            al.s[i] = f2bf(xv[i] - bf2f(h));
        }
#pragma unroll
        for (int nt = 0; nt < 4; nt++) {
            int soff = ((((kt << 2) + nt) << 6) + lane) << 4;
            bf16x8 bh = *(const bf16x8*)((const char*)WH + soff);
            bf16x8 bl = *(const bf16x8*)((const char*)WL + soff);
            acc[nt] = __builtin_amdgcn_mfma_f32_16x16x32_bf16(ah.v, bh, acc[nt], 0, 0, 0);
            acc[nt] = __builtin_amdgcn_mfma_f32_16x16x32_bf16(ah.v, bl, acc[nt], 0, 0, 0);
            acc[nt] = __builtin_amdgcn_mfma_f32_16x16x32_bf16(al.v, bh, acc[nt], 0, 0, 0);
        }
    }
    // C/D layout: col = (nt<<4)+q, row = (g<<2)+reg. Scale by dinv, store bf16.
    int rbase = tile + (wid << 4) + (g << 2);
#pragma unroll
    for (int reg = 0; reg < 4; reg++) {
        int node = rbase + reg;
        if (node < M) {
            float di = dinv[node];
            __hip_bfloat16* out = C + ((long)node << 6) + q;
#pragma unroll
            for (int nt = 0; nt < 4; nt++)
                out[nt << 4] = __float2bfloat16(acc[nt][reg] * di);
        }
    }
}

#define LO16(u) __uint_as_float((u) << 16)
#define HI16(u) __uint_as_float((u) & 0xffff0000u)
#define ACC8(v)                                            \
    do {                                                   \
        a[0] += LO16((v).x); a[1] += HI16((v).x);          \
        a[2] += LO16((v).y); a[3] += HI16((v).y);          \
        a[4] += LO16((v).z); a[5] += HI16((v).z);          \
        a[6] += LO16((v).w); a[7] += HI16((v).w);          \
    } while (0)

// fused gather + next-layer GEMM, MFMA epilogue. Block = 4 waves = 64-node tile.
// W-fragments pre-built in global (wf): phase C reads them directly (L1-resident,
// 16KB) -> LDS is only RH/RL (16KB) -> 8 blocks/CU (wave-cap) vs 5; no W-staging
// prologue. Phase B: 2 nodes per wave-round, 32 edges per shot (2 idx dwordx4 +
// 8 data dwordx4 in flight). Over-reads clamp by VALUE to zeroed guard row hs[n].
template <bool HS_OUT>
__global__ __launch_bounds__(256) void fgather_k(void* __restrict__ outp,
                                                 const __hip_bfloat16* __restrict__ hs,
                                                 const float* __restrict__ dinv,
                                                 const float* __restrict__ biasA,
                                                 const short* __restrict__ wf,
                                                 const float* __restrict__ biasB,
                                                 const int* __restrict__ rowbeg,
                                                 const int* __restrict__ rowend,
                                                 const int* __restrict__ sorted_src, int n) {
    __shared__ __align__(16) short RH[64 * 64];   // A-tile hi: [row][8 x 16B-block ^ row&7]
    __shared__ __align__(16) short RL[64 * 64];   // A-tile lo

    int t = threadIdx.x;
    int lane = t & 63;
    int wid = __builtin_amdgcn_readfirstlane(t >> 6);
    int q = lane & 15, g = lane >> 4;             // phase C coords
    int tile = blockIdx.x << 6;

    // ---- Phase B: aggregation, 2 nodes per wave-round ----
    int half = lane >> 5;                     // which node of the pair
    int g2 = (lane >> 3) & 3;                 // edge sub-stream 0..3
    int f8 = lane & 7;                        // feature octet 0..7
    int fo8 = f8 << 3;
    int rbv = 0, rev = 0;
    {
        int ndl = tile + (wid << 4) + (lane & 15);
        if (lane < 16 && ndl < n) { rbv = rowbeg[ndl]; rev = rowend[ndl]; }
    }
    __align__(16) float bb8[8];
    *(float4*)(bb8)     = *(const float4*)(biasA + fo8);
    *(float4*)(bb8 + 4) = *(const float4*)(biasA + fo8 + 4);

    for (int r = 0; r < 8; r++) {
        int row = (wid << 4) + (r << 1) + half;
        int nd = tile + row;
        int e0 = __shfl(rbv, row & 15);
        int e1 = __shfl(rev, row & 15);
        float a[8] = {0.f, 0.f, 0.f, 0.f, 0.f, 0.f, 0.f, 0.f};
        int e = e0;
        for (; e + 32 <= e1; e += 32) {       // 32 edges per node per iter
            u4u iv0 = *(const u4u*)(sorted_src + e + (g2 << 2));
            u4u iv1 = *(const u4u*)(sorted_src + e + 16 + (g2 << 2));
            uint4 v0 = *(const uint4*)(hs + (((int)iv0.x << 6) + fo8));
            uint4 v1 = *(const uint4*)(hs + (((int)iv0.y << 6) + fo8));
            uint4 v2 = *(const uint4*)(hs + (((int)iv0.z << 6) + fo8));
            uint4 v3 = *(const uint4*)(hs + (((int)iv0.w << 6) + fo8));
            uint4 v4 = *(const uint4*)(hs + (((int)iv1.x << 6) + fo8));
            uint4 v5 = *(const uint4*)(hs + (((int)iv1.y << 6) + fo8));
            uint4 v6 = *(const uint4*)(hs + (((int)iv1.z << 6) + fo8));
            uint4 v7 = *(const uint4*)(hs + (((int)iv1.w << 6) + fo8));
            ACC8(v0); ACC8(v1); ACC8(v2); ACC8(v3);
            ACC8(v4); ACC8(v5); ACC8(v6); ACC8(v7);
        }
        if (e < e1) {                         // one clamped 32-edge block
            int last = e1 - 1;
            int b0 = e + (g2 << 2);
            int b1 = b0 + 16;
            u4u iv0 = *(const u4u*)(sorted_src + b0);
            u4u iv1 = *(const u4u*)(sorted_src + b1);
            int i0 = (b0     <= last) ? (int)iv0.x : n;
            int i1 = (b0 + 1 <= last) ? (int)iv0.y : n;
            int i2 = (b0 + 2 <= last) ? (int)iv0.z : n;
            int i3 = (b0 + 3 <= last) ? (int)iv0.w : n;
            int i4 = (b1     <= last) ? (int)iv1.x : n;
            int i5 = (b1 + 1 <= last) ? (int)iv1.y : n;
            int i6 = (b1 + 2 <= last) ? (int)iv1.z : n;
            int i7 = (b1 + 3 <= last) ? (int)iv1.w : n;
            uint4 v0 = *(const uint4*)(hs + ((i0 << 6) + fo8));
            uint4 v1 = *(const uint4*)(hs + ((i1 << 6) + fo8));
            uint4 v2 = *(const uint4*)(hs + ((i2 << 6) + fo8));
            uint4 v3 = *(const uint4*)(hs + ((i3 << 6) + fo8));
            uint4 v4 = *(const uint4*)(hs + ((i4 << 6) + fo8));
            uint4 v5 = *(const uint4*)(hs + ((i5 << 6) + fo8));
            uint4 v6 = *(const uint4*)(hs + ((i6 << 6) + fo8));
            uint4 v7 = *(const uint4*)(hs + ((i7 << 6) + fo8));
            ACC8(v0); ACC8(v1); ACC8(v2); ACC8(v3);
            ACC8(v4); ACC8(v5); ACC8(v6); ACC8(v7);
        }
        // merge the 4 edge sub-streams (within each 32-lane half)
#pragma unroll
        for (int k = 0; k < 8; k++) a[k] += __shfl_xor(a[k], 8);
#pragma unroll
        for (int k = 0; k < 8; k++) a[k] += __shfl_xor(a[k], 16);
        // self-loop term (zero row for OOB)
        int snd = nd < n ? nd : n;
        uint4 sv = *(const uint4*)(hs + ((snd << 6) + fo8));
        ACC8(sv);
        float di = dinv[nd < n ? nd : 0];
        union { short s[8]; uint4 u; } ph, pl;
#pragma unroll
        for (int k = 0; k < 8; k++) {
            float rk = fmaxf(fmaf(di, a[k], bb8[k]), 0.f);
            short h = f2bf(rk);
            ph.s[k] = h;
            pl.s[k] = f2bf(rk - bf2f(h));
        }
        if (g2 == 0 && nd < n) {              // 8 lanes per half write the row
            int boff = row * 128 + ((f8 ^ (row & 7)) << 4);
            *(uint4*)((char*)RH + boff) = ph.u;
            *(uint4*)((char*)RL + boff) = pl.u;
        }
    }
    __syncthreads();                          // RH/RL staging -> Phase C

    // ---- Phase C: FC via MFMA, B-frags straight from global (L1) ----
    const bf16x8* wfv = (const bf16x8*)wf;
    f32x4 acc[4] = {};
#pragma unroll
    for (int kt = 0; kt < 2; kt++) {
        int arow = (wid << 4) + q;            // arow&7 == q&7 == write-side row&7
        int aoff = arow * 128 + ((((kt << 2) + g) ^ (q & 7)) << 4);
        bf16x8 ah = *(const bf16x8*)((const char*)RH + aoff);
        bf16x8 al = *(const bf16x8*)((const char*)RL + aoff);
#pragma unroll
        for (int nt = 0; nt < 4; nt++) {
            int sid = (((kt << 2) + nt) << 6) + lane;
            bf16x8 bh = wfv[sid];
            bf16x8 bl = wfv[512 + sid];
            acc[nt] = __builtin_amdgcn_mfma_f32_16x16x32_bf16(ah, bh, acc[nt], 0, 0, 0);
            acc[nt] = __builtin_amdgcn_mfma_f32_16x16x32_bf16(ah, bl, acc[nt], 0, 0, 0);
            acc[nt] = __builtin_amdgcn_mfma_f32_16x16x32_bf16(al, bh, acc[nt], 0, 0, 0);
        }
    }

    // ---- epilogue: C[row = (g<<2)+reg][col = (nt<<4)+q] ----
    int rbase = tile + (wid << 4);
    if (HS_OUT) {
        __hip_bfloat16* out = (__hip_bfloat16*)outp;
#pragma unroll
        for (int reg = 0; reg < 4; reg++) {
            int node = rbase + (g << 2) + reg;
            if (node < n) {
                float di = dinv[node];
#pragma unroll
                for (int nt = 0; nt < 4; nt++)
                    out[(node << 6) + (nt << 4) + q] = __float2bfloat16(acc[nt][reg] * di);
            }
        }
    } else {
        float* out = (float*)outp;
        float bB[4];
#pragma unroll
        for (int nt = 0; nt < 4; nt++) bB[nt] = biasB[(nt << 4) + q];
#pragma unroll
        for (int reg = 0; reg < 4; reg++) {
            int node = rbase + (g << 2) + reg;
            if (node < n) {
#pragma unroll
                for (int nt = 0; nt < 4; nt++)
                    out[(node << 6) + (nt << 4) + q] = acc[nt][reg] + bB[nt];
            }
        }
    }
}

extern "C" void kernel_launch(void* const* d_in, const int* in_sizes, int n_in,
                              void* d_out, int out_size, void* d_ws, size_t ws_size,
                              hipStream_t stream) {
    const float* x   = (const float*)d_in[0];
    const int*   ei  = (const int*)d_in[1];
    const float* W1  = (const float*)d_in[2];
    const float* b1  = (const float*)d_in[3];
    const float* W2  = (const float*)d_in[4];
    const float* b2  = (const float*)d_in[5];
    const float* Wfc = (const float*)d_in[6];
    const float* bfc = (const float*)d_in[7];

    int N = in_sizes[0] / INDIM;
    int E = in_sizes[1] / 2;
    const int* src = ei;       // edge_index row 0
    const int* dst = ei + E;   // edge_index row 1
    int nb = (N + BK_NODES - 1) >> BK_SHIFT;          // 782 buckets
    int cap = (2 * E / nb + 63) & ~63;                // 2x mean bucket load
    if (cap < 4096) cap = 4096;

    char* ws = (char*)d_ws;
    auto alloc = [&](size_t bytes) {
        char* p = ws;
        ws += (bytes + 15) & ~(size_t)15;
        return p;
    };
    int*   rowbeg     = (int*)alloc(sizeof(int) * (size_t)N);
    int*   rowend     = (int*)alloc(sizeof(int) * (size_t)N);
    float* dinv       = (float*)alloc(sizeof(float) * (size_t)N);
    int*   cursor     = (int*)alloc(sizeof(int) * NBK_MAX);
    int*   sorted_src = (int*)alloc(sizeof(int) * (size_t)nb * cap);
    short* wf2        = (short*)alloc(sizeof(short) * 1024 * 8);  // 16KB frag planes
    short* wffc       = (short*)alloc(sizeof(short) * 1024 * 8);
    // big region: bucketed (int, nb*cap) during build; hs2 (bf16, (N+1)*64) after
    // (lifetimes disjoint: bucketed dead after bsort_k; hs2 written by fgather<true>).
    size_t big_bytes = sizeof(int) * (size_t)nb * cap;
    size_t hs_bytes  = sizeof(__hip_bfloat16) * (size_t)(N + 1) * HID;
    char*  big       = alloc(big_bytes > hs_bytes ? big_bytes : hs_bytes);
    int*   bucketed  = (int*)big;
    __hip_bfloat16* hs2 = (__hip_bfloat16*)big;
    // hs1 lives in d_out (25.6MB f32 region; hs1 needs 12.8MB bf16 + guard row).
    // Dead before fgather<false> overwrites d_out with the final f32 output.
    __hip_bfloat16* hs1 = (__hip_bfloat16*)d_out;
    float* outp      = (float*)d_out;

    hipMemsetAsync(cursor, 0, sizeof(int) * NBK_MAX, stream);
    // hs1 guard row (in d_out scratch): nothing touches d_out before gemm1.
    hipMemsetAsync((char*)hs1 + (size_t)N * HID * 2, 0, HID * 2, stream);

    bpart_k<<<PB_BLOCKS, 256, 0, stream>>>(src, dst, cursor, bucketed, E, cap);
    bsort_k<<<nb + 2, 256, 0, stream>>>(bucketed, cursor, rowbeg, rowend, sorted_src,
                                        dinv, N, cap, nb, W2, Wfc, wf2, wffc);
    // hs2 guard row (big region free of bucketed only after bsort_k)
    hipMemsetAsync((char*)hs2 + (size_t)N * HID * 2, 0, HID * 2, stream);

    gemm1_k<<<(N + 63) / 64, 256, 0, stream>>>(x, W1, dinv, hs1, N);
    fgather_k<true><<<(N + 63) / 64, 256, 0, stream>>>(hs2, hs1, dinv, b1, wf2, nullptr,
                                                       rowbeg, rowend, sorted_src, N);
    fgather_k<false><<<(N + 63) / 64, 256, 0, stream>>>(outp, hs2, dinv, b2, wffc, bfc,
                                                        rowbeg, rowend, sorted_src, N);
}